// Round 7
// baseline (223.697 us; speedup 1.0000x reference)
//
#include <hip/hip_runtime.h>
#include <hip/hip_bf16.h>
#include <stdint.h>

// GPTQ int4 linear via bf16 MFMA. M=32, K=8192, N=8192, group=64.
// R7: non-temporal pw stream. Theory: the harness's 512 MB d_ws 0xAA fill
// leaves L3 full of dirty junk; our 128 MB pw read-misses were forcing ~250 MB
// of junk writebacks (the invariant ~60 us across R3-R6). NT loads (no LLC
// allocate) should cut main-kernel HBM traffic to the pure 128 MB stream.
// Structure: register-pipeline K-loop (proven R4 path), KSPLIT=1, grid 512,
// scales/zeros in registers, direct stores with bias, no atomics.

#define KK 8192
#define NN 8192
#define KP 4096      // int32 per weight row
#define NG 128       // quant groups per row
#define BN 16        // n per block
#define KSW 64       // ksteps (32 k) per wave: 4 waves * 64 * 32 = 8192
#define NKS 256      // total ksteps
#define KSPLIT 2     // fallback only

typedef __attribute__((ext_vector_type(8))) short short8;
typedef __attribute__((ext_vector_type(4))) float floatx4;
typedef __attribute__((ext_vector_type(4))) int int4v;

__device__ __forceinline__ unsigned pack_bf16x2(float lo, float hi) {
    union { __hip_bfloat162 h; unsigned u; } c;
    c.h = __float22bfloat162_rn(make_float2(lo, hi));
    return c.u;
}

// dequant 2 nibbles -> packed bf16x2 (RNE; w finite, no NaN path)
__device__ __forceinline__ unsigned dq2(int q, float sc, float zs) {
    float lo = fmaf((float)(q & 15),        sc, zs);
    float hi = fmaf((float)((q >> 4) & 15), sc, zs);
    unsigned ua = __float_as_uint(lo); ua += 0x7fffu + ((ua >> 16) & 1u);
    unsigned ub = __float_as_uint(hi); ub += 0x7fffu + ((ub >> 16) & 1u);
    return __builtin_amdgcn_perm(ub, ua, 0x07060302);   // [ub.hi16 : ua.hi16]
}

// blocks [0,xconv_blocks): x fp32 -> bf16 A-frags in xb; rest: out = bias fill.
__global__ void prep_kernel(const float* __restrict__ x, const float* __restrict__ bias,
                            ushort* __restrict__ xb, float* __restrict__ out,
                            int xconv_blocks)
{
    const int bx = blockIdx.x;
    if (bx < xconv_blocks) {
        const int tid = bx * 256 + threadIdx.x;   // 0..32767
        const int l   = tid & 63;
        const int ks  = (tid >> 6) & 255;
        const int mt  = tid >> 14;
        const int m   = (l & 15) + 16 * mt;
        const int kb  = ks * 32 + (l >> 4) * 8;
        const float* src = x + (size_t)m * KK + kb;
        const float4 a = *(const float4*)(src);
        const float4 b = *(const float4*)(src + 4);
        *(uint4*)(xb + (size_t)tid * 8) =
            make_uint4(pack_bf16x2(a.x, a.y), pack_bf16x2(a.z, a.w),
                       pack_bf16x2(b.x, b.y), pack_bf16x2(b.z, b.w));
    } else {
        const int f4 = (bx - xconv_blocks) * 256 + threadIdx.x;  // 0..65535
        const int n4 = f4 & (NN / 4 - 1);
        ((float4*)out)[f4] = ((const float4*)bias)[n4];
    }
}

__global__ __launch_bounds__(256, 2)
void gptq_mfma_main(const int*   __restrict__ pw,
                    const float* __restrict__ scales,
                    const float* __restrict__ zeros,
                    const float* __restrict__ bias,
                    const ushort* __restrict__ xb,
                    float* __restrict__ out)
{
    __shared__ float red[4][2][256];

    const int tid  = threadIdx.x;
    const int lane = tid & 63;
    const int wave = tid >> 6;
    const int n0   = blockIdx.x * BN;
    const int nl   = lane & 15;     // B-frag col (n_local)
    const int kq   = lane >> 4;     // k-quad
    const int ks0  = wave * KSW;    // this wave's first kstep

    // ---- scales/zeros -> registers: 32 groups per wave ----
    float scr[32], zsr[32];
    {
        const float* sp = scales + (size_t)(n0 + nl) * NG + wave * 32;
        const float* zp = zeros  + (size_t)(n0 + nl) * NG + wave * 32;
#pragma unroll
        for (int i = 0; i < 8; ++i) {
            const float4 s4 = *(const float4*)(sp + i * 4);
            const float4 z4 = *(const float4*)(zp + i * 4);
            scr[i*4+0] = s4.x; zsr[i*4+0] = -z4.x * s4.x;
            scr[i*4+1] = s4.y; zsr[i*4+1] = -z4.y * s4.y;
            scr[i*4+2] = s4.z; zsr[i*4+2] = -z4.z * s4.z;
            scr[i*4+3] = s4.w; zsr[i*4+3] = -z4.w * s4.w;
        }
    }

    const int* pwp = pw + (size_t)(n0 + nl) * KP + kq * 4;
    const uint4* xfp = (const uint4*)xb;

    floatx4 acc0 = {0.f, 0.f, 0.f, 0.f};
    floatx4 acc1 = {0.f, 0.f, 0.f, 0.f};

    int4v pwb[4];
    uint4 x0b[4], x1b[4];

#pragma unroll
    for (int i = 0; i < 3; ++i) {
        const int ks = ks0 + i;
        pwb[i] = __builtin_nontemporal_load((const int4v*)(pwp + ks * 16));
        x0b[i] = xfp[(size_t)(0 * NKS + ks) * 64 + lane];
        x1b[i] = xfp[(size_t)(1 * NKS + ks) * 64 + lane];
    }

#pragma unroll 4
    for (int i = 0; i < KSW; ++i) {
        const int slot = i & 3;
        if (i + 3 < KSW) {
            const int ks = ks0 + i + 3;
            const int ps = (i + 3) & 3;
            pwb[ps] = __builtin_nontemporal_load((const int4v*)(pwp + ks * 16));
            x0b[ps] = xfp[(size_t)(0 * NKS + ks) * 64 + lane];
            x1b[ps] = xfp[(size_t)(1 * NKS + ks) * 64 + lane];
        }
        const float sc = scr[i >> 1];
        const float zs = zsr[i >> 1];

        union { uint4 v; short8 sv; } bf, a0, a1;
        const int4v p = pwb[slot];
        bf.v.x = dq2(p.x, sc, zs);
        bf.v.y = dq2(p.y, sc, zs);
        bf.v.z = dq2(p.z, sc, zs);
        bf.v.w = dq2(p.w, sc, zs);
        a0.v = x0b[slot];
        a1.v = x1b[slot];
        acc0 = __builtin_amdgcn_mfma_f32_16x16x32_bf16(a0.sv, bf.sv, acc0, 0, 0, 0);
        acc1 = __builtin_amdgcn_mfma_f32_16x16x32_bf16(a1.sv, bf.sv, acc1, 0, 0, 0);
    }

    // ---- epilogue: cross-wave reduce via LDS, direct NT store + bias ----
#pragma unroll
    for (int r = 0; r < 4; ++r) {
        const int row = kq * 4 + r;
        red[wave][0][row * 16 + nl] = acc0[r];
        red[wave][1][row * 16 + nl] = acc1[r];
    }
    __syncthreads();

#pragma unroll
    for (int i = 0; i < 2; ++i) {
        const int e   = i * 256 + tid;
        const int mt  = e >> 8;
        const int idx = e & 255;
        const float sv = red[0][mt][idx] + red[1][mt][idx]
                       + red[2][mt][idx] + red[3][mt][idx];
        const int n = n0 + (idx & 15);
        __builtin_nontemporal_store(sv + bias[n],
            out + (size_t)(mt * 16 + (idx >> 4)) * NN + n);
    }
}

// Fallback (no workspace): register-path kernel, direct fp32 x loads, atomics.
__global__ __launch_bounds__(256, 4)
void gptq_mfma_fallback(const int*   __restrict__ pw,
                        const float* __restrict__ scales,
                        const float* __restrict__ zeros,
                        const float* __restrict__ x,
                        float* __restrict__ out)
{
    __shared__ float s_lds[64][BN + 1];
    __shared__ float z_lds[64][BN + 1];
    __shared__ float red[4][2][256];

    const int tid  = threadIdx.x;
    const int lane = tid & 63;
    const int wave = tid >> 6;
    const int kh   = blockIdx.x & (KSPLIT - 1);
    const int n0   = (blockIdx.x >> 1) * BN;
    const int g0   = kh * 64;

    {
        const int r  = tid >> 4;
        const int gb = (tid & 15) * 4;
        const float4 s4 = *(const float4*)(scales + (size_t)(n0 + r) * NG + g0 + gb);
        const float4 z4 = *(const float4*)(zeros  + (size_t)(n0 + r) * NG + g0 + gb);
        s_lds[gb + 0][r] = s4.x; s_lds[gb + 1][r] = s4.y;
        s_lds[gb + 2][r] = s4.z; s_lds[gb + 3][r] = s4.w;
        z_lds[gb + 0][r] = z4.x; z_lds[gb + 1][r] = z4.y;
        z_lds[gb + 2][r] = z4.z; z_lds[gb + 3][r] = z4.w;
    }
    __syncthreads();

    const int nl = lane & 15;
    const int kq = lane >> 4;
    const int* pwp = pw + (size_t)(n0 + nl) * KP + kq * 4;
    const int ks0 = kh * 128 + wave * 32;

    auto load_xfrag = [&](int mt, int ks) -> uint4 {
        const float* src = x + (size_t)(nl + 16 * mt) * KK + ks * 32 + kq * 8;
        const float4 a = *(const float4*)(src);
        const float4 b = *(const float4*)(src + 4);
        return make_uint4(pack_bf16x2(a.x, a.y), pack_bf16x2(a.z, a.w),
                          pack_bf16x2(b.x, b.y), pack_bf16x2(b.z, b.w));
    };

    floatx4 acc0 = {0.f, 0.f, 0.f, 0.f};
    floatx4 acc1 = {0.f, 0.f, 0.f, 0.f};
    int4v pwb[4];
    uint4 x0b[4], x1b[4];

#pragma unroll
    for (int i = 0; i < 3; ++i) {
        const int ks = ks0 + i;
        pwb[i] = __builtin_nontemporal_load((const int4v*)(pwp + ks * 16));
        x0b[i] = load_xfrag(0, ks);
        x1b[i] = load_xfrag(1, ks);
    }

#pragma unroll 4
    for (int i = 0; i < 32; ++i) {
        const int slot = i & 3;
        if (i + 3 < 32) {
            const int ks = ks0 + i + 3;
            const int ps = (i + 3) & 3;
            pwb[ps] = __builtin_nontemporal_load((const int4v*)(pwp + ks * 16));
            x0b[ps] = load_xfrag(0, ks);
            x1b[ps] = load_xfrag(1, ks);
        }
        const int gl  = (wave * 32 + i) >> 1;
        const float sc = s_lds[gl][nl];
        const float zs = -z_lds[gl][nl] * sc;

        union { uint4 v; short8 sv; } bf, a0, a1;
        const int4v p = pwb[slot];
        bf.v.x = dq2(p.x, sc, zs);
        bf.v.y = dq2(p.y, sc, zs);
        bf.v.z = dq2(p.z, sc, zs);
        bf.v.w = dq2(p.w, sc, zs);
        a0.v = x0b[slot];
        a1.v = x1b[slot];
        acc0 = __builtin_amdgcn_mfma_f32_16x16x32_bf16(a0.sv, bf.sv, acc0, 0, 0, 0);
        acc1 = __builtin_amdgcn_mfma_f32_16x16x32_bf16(a1.sv, bf.sv, acc1, 0, 0, 0);
    }

#pragma unroll
    for (int r = 0; r < 4; ++r) {
        const int row = kq * 4 + r;
        red[wave][0][row * 16 + nl] = acc0[r];
        red[wave][1][row * 16 + nl] = acc1[r];
    }
    __syncthreads();

#pragma unroll
    for (int i = 0; i < 2; ++i) {
        const int e   = i * 256 + tid;
        const int mt  = e >> 8;
        const int idx = e & 255;
        const float s = red[0][mt][idx] + red[1][mt][idx] + red[2][mt][idx] + red[3][mt][idx];
        atomicAdd(out + (size_t)(mt * 16 + (idx >> 4)) * NN + n0 + (idx & 15), s);
    }
}

extern "C" void kernel_launch(void* const* d_in, const int* in_sizes, int n_in,
                              void* d_out, int out_size, void* d_ws, size_t ws_size,
                              hipStream_t stream) {
    const float* x      = (const float*)d_in[0];
    const int*   pw     = (const int*)  d_in[1];
    const float* scales = (const float*)d_in[2];
    const float* zeros  = (const float*)d_in[3];
    const float* bias   = (const float*)d_in[4];
    float* out = (float*)d_out;

    const size_t need = (size_t)32768 * 16;   // 512 KB of bf16 A-frags
    if (d_ws != nullptr && ws_size >= need) {
        ushort* xb = (ushort*)d_ws;
        prep_kernel<<<128, 256, 0, stream>>>(x, bias, xb, out, 128);   // xconv only
        gptq_mfma_main<<<NN / BN, 256, 0, stream>>>(pw, scales, zeros, bias, xb, out);
    } else {
        prep_kernel<<<256, 256, 0, stream>>>(x, bias, nullptr, out, 0); // bias fill
        gptq_mfma_fallback<<<512 * KSPLIT, 256, 0, stream>>>(pw, scales, zeros, x, out);
    }
}